// Round 11
// baseline (209.651 us; speedup 1.0000x reference)
//
#include <hip/hip_runtime.h>
#include <hip/hip_bf16.h>

// Problem constants (B=2, T=2048, C=1024, NH=16, NKV=8, HD=64, Q_PER_KV=2)
#define BB 2
#define TT 2048
#define CC 1024
#define NH 16
#define NKV 8
#define HD 64

typedef __attribute__((ext_vector_type(8))) short short8;   // 8 bf16 (MFMA A/B frag)
typedef __attribute__((ext_vector_type(4))) float float4v;  // MFMA C/D frag
typedef __attribute__((ext_vector_type(4))) unsigned int uint4v;

__device__ __forceinline__ ushort f2bf(float f) {
    __hip_bfloat16 h = __float2bfloat16(f);
    union { __hip_bfloat16 h; ushort u; } v; v.h = h; return v.u;
}
__device__ __forceinline__ float bf2f(ushort u) {
    union { unsigned int i; float f; } v; v.i = ((unsigned int)u) << 16; return v.f;
}

// exp2 on the transcendental pipe; scale is folded by caller.
__device__ __forceinline__ float fexp2(float x) {
#if __has_builtin(__builtin_amdgcn_exp2f)
    return __builtin_amdgcn_exp2f(x);
#else
    return __expf(x * 0.69314718056f);
#endif
}

// async global->LDS, 16B per lane; lptr must be wave-uniform, HW adds lane*16
__device__ __forceinline__ void gload16(const ushort* g, ushort* l) {
    __builtin_amdgcn_global_load_lds(
        (const __attribute__((address_space(1))) unsigned int*)g,
        (__attribute__((address_space(3))) unsigned int*)l, 16, 0, 0);
}

// ---------------------------------------------------------------------------
// Fused prep: x f32->bf16 conv + per-row gate (blocks 0..4095) + weight
// transposes (f32 [K][N] -> bf16 [N][K], 64x64 LDS tiles).
// ---------------------------------------------------------------------------
__device__ __forceinline__ void transpose_tile(
    const float* __restrict__ src, ushort* __restrict__ dst,
    int Kd, int Nd, int kt, int nt, float* tile /*[64][65]*/)
{
    const int tid = threadIdx.x;
    {
        int r = tid >> 2, c = (tid & 3) * 16;
        #pragma unroll
        for (int i = 0; i < 4; i++) {
            float4 v = *(const float4*)&src[(size_t)(kt + r) * Nd + nt + c + i * 4];
            tile[r * 65 + c + i * 4 + 0] = v.x;
            tile[r * 65 + c + i * 4 + 1] = v.y;
            tile[r * 65 + c + i * 4 + 2] = v.z;
            tile[r * 65 + c + i * 4 + 3] = v.w;
        }
    }
    __syncthreads();
    {
        int n = tid >> 2, k = (tid & 3) * 16;
        #pragma unroll
        for (int i = 0; i < 2; i++) {
            ushort u[8];
            #pragma unroll
            for (int j = 0; j < 8; j++) u[j] = f2bf(tile[(k + i * 8 + j) * 65 + n]);
            *(uint4*)&dst[(size_t)(nt + n) * Kd + kt + k + i * 8] = *(uint4*)u;
        }
    }
}

__global__ __launch_bounds__(256) void prep_kernel(
    const float* __restrict__ x, ushort* __restrict__ xb,
    const float* __restrict__ Wq, const float* __restrict__ Wk,
    const float* __restrict__ Wv, const float* __restrict__ Wproj,
    const float* __restrict__ wgate,
    ushort* __restrict__ WqkvT, ushort* __restrict__ WpT,
    float* __restrict__ gateP)
{
    __shared__ float tile[64 * 65];
    const int bid = blockIdx.x;
    if (bid < 4096) {
        int i = (bid * 256 + threadIdx.x) * 4;
        float4 v = *(const float4*)&x[i];
        xb[i + 0] = f2bf(v.x);
        xb[i + 1] = f2bf(v.y);
        xb[i + 2] = f2bf(v.z);
        xb[i + 3] = f2bf(v.w);
        // gate for this row: gate[bid][g] = 2*sigmoid(sum_i x[bid][i]*Wgate[i][g])
        {
            int g = threadIdx.x >> 5, ii = threadIdx.x & 31;
            float p = x[(size_t)bid * CC + ii] * wgate[ii * 8 + g];
            #pragma unroll
            for (int off = 16; off; off >>= 1) p += __shfl_down(p, off, 32);
            if (ii == 0) gateP[bid * 8 + g] = 2.f / (1.f + __expf(-p));
        }
        return;
    }
    int t = bid - 4096;
    if (t < 256) {
        transpose_tile(Wq, WqkvT, 1024, 1024, (t >> 4) * 64, (t & 15) * 64, tile);
    } else if (t < 384) {
        t -= 256;
        transpose_tile(Wk, WqkvT + (size_t)1024 * 1024, 1024, 512, (t >> 3) * 64, (t & 7) * 64, tile);
    } else if (t < 512) {
        t -= 384;
        transpose_tile(Wv, WqkvT + (size_t)1536 * 1024, 1024, 512, (t >> 3) * 64, (t & 7) * 64, tile);
    } else {
        t -= 512;
        transpose_tile(Wproj, WpT, 1024, 1024, (t >> 4) * 64, (t & 15) * 64, tile);
    }
}

// ---------------------------------------------------------------------------
// bf16 GEMM — EXACT r4 single-buffer BK=32 form (5 rounds passing pedigree
// at absmax 0.015625; the same-buffer stage->read hazard makes the compiler
// emit the pre-barrier vmcnt drain, per the m97 asm). The r10 explicit
// vmcnt0 is dropped: redundant for correctness here and its "memory"
// clobber acted as a scheduling barrier (+~6us total).
// ---------------------------------------------------------------------------
template<int BM, int OBF16>
__global__ __launch_bounds__(256) void gemm_bt_kernel(
    const ushort* __restrict__ A, const ushort* __restrict__ Bt,
    void* __restrict__ Cp, int M, int N, int K, int ldc)
{
    constexpr int RT = BM / 32;
    __shared__ ushort As[BM][32];
    __shared__ ushort Bs[128][32];

    const int m0 = blockIdx.x * BM;
    const int n0 = blockIdx.y * 128;
    const int tid = threadIdx.x;
    const int lane = tid & 63;
    const int w = tid >> 6;
    const int lr = lane & 15, lc = lane >> 4;
    const int wm = (w >> 1) * (BM / 2), wn = (w & 1) * 64;

    float4v acc[RT][4] = {};

    for (int k0 = 0; k0 < K; k0 += 32) {
        #pragma unroll
        for (int s = 0; s < BM / 64; s++) {
            int rb = w * (BM / 4) + s * 16;
            gload16(&A[(size_t)(m0 + rb + (lane >> 2)) * K + k0 + (lane & 3) * 8], &As[rb][0]);
        }
        #pragma unroll
        for (int s = 0; s < 2; s++) {
            int rb = w * 32 + s * 16;
            gload16(&Bt[(size_t)(n0 + rb + (lane >> 2)) * K + k0 + (lane & 3) * 8], &Bs[rb][0]);
        }
        __syncthreads();

        short8 af[RT], bf[4];
        #pragma unroll
        for (int t = 0; t < RT; t++)
            af[t] = *(const short8*)&As[wm + t * 16 + lr][lc * 8];
        #pragma unroll
        for (int t = 0; t < 4; t++)
            bf[t] = *(const short8*)&Bs[wn + t * 16 + lr][lc * 8];
        #pragma unroll
        for (int rt = 0; rt < RT; rt++)
            #pragma unroll
            for (int ct = 0; ct < 4; ct++)
                acc[rt][ct] = __builtin_amdgcn_mfma_f32_16x16x32_bf16(af[rt], bf[ct], acc[rt][ct], 0, 0, 0);
        __syncthreads();
    }

    #pragma unroll
    for (int rt = 0; rt < RT; rt++)
        #pragma unroll
        for (int ct = 0; ct < 4; ct++)
            #pragma unroll
            for (int r = 0; r < 4; r++) {
                int row = m0 + wm + rt * 16 + lc * 4 + r;
                int col = n0 + wn + ct * 16 + lr;
                if (OBF16) ((ushort*)Cp)[(size_t)row * ldc + col] = f2bf(acc[rt][ct][r]);
                else       ((float*)Cp)[(size_t)row * ldc + col] = acc[rt][ct][r];
            }
}

// ---------------------------------------------------------------------------
// Fused QKV GEMM — exact r4 single-buffer BK=32 loop. Epilogue applies
// RoPE+RMSNorm (Q/K) or gate+ve add (V) on the UNROUNDED f32 accumulators.
// THIS ROUND: the V branch writes V^T (B,NKV,HD,T) DIRECTLY — the epilogue
// holds each element as (d = lr+16k, t = row), so Vt[(bh*HD+d)*TT+t] is a
// pure re-address of the same stores. This deletes the v_transpose kernel,
// its launch gap, and the 8 MB Vn round-trip. Index algebra verified against
// the old transpose kernel: Vt[bh*HD*TT + d*TT + t] = Vn[bh*TT*HD + t*HD+d].
// Per-wave writes collectively cover full (d, 64-t) 128B spans -> L2
// write-combining keeps HBM write traffic at the same 4 MB.
// ---------------------------------------------------------------------------
__global__ __launch_bounds__(256) void gemm_qkv_kernel(
    const ushort* __restrict__ A, const ushort* __restrict__ Bt,
    const float* __restrict__ cosb, const float* __restrict__ sinb,
    const float* __restrict__ gateP, const float* __restrict__ ve,
    ushort* __restrict__ Qb, ushort* __restrict__ Kb, ushort* __restrict__ Vt)
{
    constexpr int K = 1024;
    __shared__ ushort As[128][32];
    __shared__ ushort Bs[128][32];

    const int m0 = blockIdx.x * 128;
    const int n0 = blockIdx.y * 128;
    const int tid = threadIdx.x;
    const int lane = tid & 63;
    const int w = tid >> 6;
    const int lr = lane & 15, lc = lane >> 4;
    const int wm = (w >> 1) * 64, wn = (w & 1) * 64;

    float4v acc[4][4] = {};

    for (int k0 = 0; k0 < K; k0 += 32) {
        #pragma unroll
        for (int s = 0; s < 2; s++) {
            int rb = w * 32 + s * 16;
            gload16(&A[(size_t)(m0 + rb + (lane >> 2)) * K + k0 + (lane & 3) * 8], &As[rb][0]);
            gload16(&Bt[(size_t)(n0 + rb + (lane >> 2)) * K + k0 + (lane & 3) * 8], &Bs[rb][0]);
        }
        __syncthreads();

        short8 af[4], bf[4];
        #pragma unroll
        for (int t = 0; t < 4; t++)
            af[t] = *(const short8*)&As[wm + t * 16 + lr][lc * 8];
        #pragma unroll
        for (int t = 0; t < 4; t++)
            bf[t] = *(const short8*)&Bs[wn + t * 16 + lr][lc * 8];
        #pragma unroll
        for (int rt = 0; rt < 4; rt++)
            #pragma unroll
            for (int ct = 0; ct < 4; ct++)
                acc[rt][ct] = __builtin_amdgcn_mfma_f32_16x16x32_bf16(af[rt], bf[ct], acc[rt][ct], 0, 0, 0);
        __syncthreads();
    }

    const int cg = n0 + wn;        // wave col base, multiple of 64
    const int hh2 = cg >> 6;       // 0..15 Q head, 16..23 K head, 24..31 V head

    if (hh2 < 24) {
        // ---- Q/K: RoPE + RMSNorm on f32 acc ----
        #pragma unroll
        for (int rt = 0; rt < 4; rt++) {
            #pragma unroll
            for (int r = 0; r < 4; r++) {
                int row = m0 + wm + rt * 16 + lc * 4 + r;
                int b = row >> 11, t = row & 2047;
                float v0 = acc[rt][0][r], v1 = acc[rt][1][r];
                float v2 = acc[rt][2][r], v3 = acc[rt][3][r];
                const float* cp = &cosb[t * 32];
                const float* sp = &sinb[t * 32];
                float c0 = cp[lr], s0 = sp[lr];
                float c1 = cp[16 + lr], s1 = sp[16 + lr];
                float r0 = v0 * c0 + v2 * s0;          // out[d],    d = lr
                float r1 = v1 * c1 + v3 * s1;          // out[d],    d = 16+lr
                float r2 = v2 * c0 - v0 * s0;          // out[32+lr]
                float r3 = v3 * c1 - v1 * s1;          // out[48+lr]
                float ss = (r0 * r0 + r1 * r1) + (r2 * r2 + r3 * r3);
                ss += __shfl_xor(ss, 1);
                ss += __shfl_xor(ss, 2);
                ss += __shfl_xor(ss, 4);
                ss += __shfl_xor(ss, 8);
                float sc = rsqrtf(ss * (1.f / 64.f) + 1.1920929e-07f);
                ushort* op = (hh2 < 16)
                    ? &Qb[(((size_t)b * NH + hh2) * TT + t) * HD]
                    : &Kb[(((size_t)b * NKV + (hh2 - 16)) * TT + t) * HD];
                op[lr]      = f2bf(r0 * sc);
                op[16 + lr] = f2bf(r1 * sc);
                op[32 + lr] = f2bf(r2 * sc);
                op[48 + lr] = f2bf(r3 * sc);
            }
        }
    } else {
        // ---- V: gate + ve add, written DIRECTLY as V^T (B,NKV,HD,T) ----
        const int kvh = hh2 - 24;
        #pragma unroll
        for (int rt = 0; rt < 4; rt++) {
            #pragma unroll
            for (int r = 0; r < 4; r++) {
                int row = m0 + wm + rt * 16 + lc * 4 + r;
                int b = row >> 11, t = row & 2047;
                float g = gateP[row * 8 + kvh];
                const float* vp = &ve[(size_t)row * 512 + kvh * 64];
                ushort* opT = &Vt[((size_t)(b * NKV + kvh) * HD) * TT + t];
                opT[(size_t)(lr)      * TT] = f2bf(acc[rt][0][r] + g * vp[lr]);
                opT[(size_t)(16 + lr) * TT] = f2bf(acc[rt][1][r] + g * vp[16 + lr]);
                opT[(size_t)(32 + lr) * TT] = f2bf(acc[rt][2][r] + g * vp[32 + lr]);
                opT[(size_t)(48 + lr) * TT] = f2bf(acc[rt][3][r] + g * vp[48 + lr]);
            }
        }
    }
}

// ---------------------------------------------------------------------------
// Split-KV flash attention (static r4 inner structure, T12 in-reg P
// transpose) + T1 XCD-panel swizzle (kept from r10: FETCH 12.35->8.25 MB,
// dur-neutral; bijective, numerically identical per item). FROZEN — all
// macro levers (occupancy r7, balance r7, locality r10) measured
// neutral-or-worse on dur; the kernel is dependency-latency-bound.
// ---------------------------------------------------------------------------
__global__ __launch_bounds__(256) void attn_kernel(
    const ushort* __restrict__ Qb, const ushort* __restrict__ Kb,
    const ushort* __restrict__ Vt, ushort* __restrict__ Yb,
    const int* __restrict__ winp)
{
    const int bid = blockIdx.x;
    const int p = bid & 7;          // XCD panel
    const int rank = bid >> 3;      // 0..255 within panel (heavy-first)
    const int rtype = rank >> 7;    // 0 = global heads, 1 = local heads
    const int rr = rank & 127;
    const int qw = 63 - (rr >> 1);
    const int h = (rtype ? 8 : 0) + (p >> 1) * 2 + (rr & 1);
    const int b = p & 1;

    const int q0 = qw * 32;
    const int kvh = h >> 1;
    const bool local = (h >= 8);
    int window = *winp;
    if (window < 0 || window > TT) window = TT;
    const int tid = threadIdx.x;
    const int w = tid >> 6;
    const int lane = tid & 63;
    const int lr = lane & 15, lc = lane >> 4;

    __shared__ float4v Ol[4][4][64];
    __shared__ float Ll[4][16];

    const ushort* qbase = &Qb[(((size_t)b * NH + h) * TT + q0) * HD];
    short8 qf[2][2];
    #pragma unroll
    for (int rt = 0; rt < 2; rt++)
        #pragma unroll
        for (int xh = 0; xh < 2; xh++)
            qf[rt][xh] = *(const short8*)&qbase[(size_t)(rt * 16 + lr) * HD + xh * 32 + lc * 8];

    float4v o[2][4] = {};
    float l_[2] = {0.f, 0.f};

    const ushort* Kbase = &Kb[((size_t)b * NKV + kvh) * TT * HD];
    const ushort* Vbase = &Vt[((size_t)b * NKV + kvh) * HD * TT];

    const int qlast = q0 + 31;
    int jstart = 0;
    if (local) { int js = q0 - window; if (js > 0) jstart = js & ~63; }
    const int j0first = jstart + w * 64;

    // softmax scale (1/8) folded into exp2: exp(x/8) = 2^(x * 0.125*log2(e))
    const float ESC = 0.1803368801f;

    short8 kf[4][2];
    if (j0first <= qlast) {
        #pragma unroll
        for (int jt = 0; jt < 4; jt++) {
            const ushort* kp = &Kbase[(size_t)(j0first + jt * 16 + lr) * HD + lc * 8];
            kf[jt][0] = *(const short8*)kp;
            kf[jt][1] = *(const short8*)(kp + 32);
        }
    }

    for (int j0 = j0first; j0 <= qlast; j0 += 256) {
        short8 vf[4][2];
        #pragma unroll
        for (int ct = 0; ct < 4; ct++) {
            const ushort* vp = &Vbase[(size_t)(ct * 16 + lr) * TT + j0 + lc * 8];
            vf[ct][0] = *(const short8*)vp;
            vf[ct][1] = *(const short8*)(vp + 32);
        }
        short8 kn[4][2];
        const bool more = (j0 + 256 <= qlast);
        if (more) {
            #pragma unroll
            for (int jt = 0; jt < 4; jt++) {
                const ushort* kp = &Kbase[(size_t)(j0 + 256 + jt * 16 + lr) * HD + lc * 8];
                kn[jt][0] = *(const short8*)kp;
                kn[jt][1] = *(const short8*)(kp + 32);
            }
        }

        float4v st[2][4];
        #pragma unroll
        for (int jt = 0; jt < 4; jt++)
            #pragma unroll
            for (int rt = 0; rt < 2; rt++) {
                float4v z = {};
                z = __builtin_amdgcn_mfma_f32_16x16x32_bf16(kf[jt][0], qf[rt][0], z, 0, 0, 0);
                z = __builtin_amdgcn_mfma_f32_16x16x32_bf16(kf[jt][1], qf[rt][1], z, 0, 0, 0);
                st[rt][jt] = z;
            }

        const bool need_c = (j0 + 63 > q0);
        const bool need_w = local && (j0 < qlast - window);

        #pragma unroll
        for (int rt = 0; rt < 2; rt++) {
            const int qrow = q0 + rt * 16 + lr;
            float p4[4][4];
            if (need_c || need_w) {
                #pragma unroll
                for (int jt = 0; jt < 4; jt++)
                    #pragma unroll
                    for (int r = 0; r < 4; r++) {
                        int key = j0 + jt * 16 + lc * 4 + r;
                        bool ok = (key <= qrow) && (!local || key >= qrow - window);
                        p4[jt][r] = ok ? fexp2(st[rt][jt][r] * ESC) : 0.f;
                    }
            } else {
                #pragma unroll
                for (int jt = 0; jt < 4; jt++)
                    #pragma unroll
                    for (int r = 0; r < 4; r++)
                        p4[jt][r] = fexp2(st[rt][jt][r] * ESC);
            }
            float s0 = (p4[0][0] + p4[0][1]) + (p4[0][2] + p4[0][3]);
            float s1 = (p4[1][0] + p4[1][1]) + (p4[1][2] + p4[1][3]);
            float s2 = (p4[2][0] + p4[2][1]) + (p4[2][2] + p4[2][3]);
            float s3 = (p4[3][0] + p4[3][1]) + (p4[3][2] + p4[3][3]);
            l_[rt] += (s0 + s1) + (s2 + s3);

            // ---- T12: in-register P -> B-fragment transpose ----
            unsigned int a0, a1, b0, b1, c0, c1, d0, d1;
            asm("v_cvt_pk_bf16_f32 %0, %1, %2" : "=v"(a0) : "v"(p4[0][0]), "v"(p4[0][1]));
            asm("v_cvt_pk_bf16_f32 %0, %1, %2" : "=v"(a1) : "v"(p4[0][2]), "v"(p4[0][3]));
            asm("v_cvt_pk_bf16_f32 %0, %1, %2" : "=v"(b0) : "v"(p4[1][0]), "v"(p4[1][1]));
            asm("v_cvt_pk_bf16_f32 %0, %1, %2" : "=v"(b1) : "v"(p4[1][2]), "v"(p4[1][3]));
            asm("v_cvt_pk_bf16_f32 %0, %1, %2" : "=v"(c0) : "v"(p4[2][0]), "v"(p4[2][1]));
            asm("v_cvt_pk_bf16_f32 %0, %1, %2" : "=v"(c1) : "v"(p4[2][2]), "v"(p4[2][3]));
            asm("v_cvt_pk_bf16_f32 %0, %1, %2" : "=v"(d0) : "v"(p4[3][0]), "v"(p4[3][1]));
            asm("v_cvt_pk_bf16_f32 %0, %1, %2" : "=v"(d1) : "v"(p4[3][2]), "v"(p4[3][3]));

            asm("v_permlane32_swap_b32 %0, %1" : "+v"(a0), "+v"(b0));
            asm("v_permlane16_swap_b32 %0, %1" : "+v"(a0), "+v"(b0));
            asm("v_permlane32_swap_b32 %0, %1" : "+v"(a1), "+v"(b1));
            asm("v_permlane16_swap_b32 %0, %1" : "+v"(a1), "+v"(b1));
            asm("v_permlane32_swap_b32 %0, %1" : "+v"(c0), "+v"(d0));
            asm("v_permlane16_swap_b32 %0, %1" : "+v"(c0), "+v"(d0));
            asm("v_permlane32_swap_b32 %0, %1" : "+v"(c1), "+v"(d1));
            asm("v_permlane16_swap_b32 %0, %1" : "+v"(c1), "+v"(d1));

            uint4v u0 = {a0, a1, b0, b1};
            uint4v u1 = {c0, c1, d0, d1};
            short8 P0 = __builtin_bit_cast(short8, u0);
            short8 P1 = __builtin_bit_cast(short8, u1);

            #pragma unroll
            for (int ct = 0; ct < 4; ct++) {
                o[rt][ct] = __builtin_amdgcn_mfma_f32_16x16x32_bf16(vf[ct][0], P0, o[rt][ct], 0, 0, 0);
                o[rt][ct] = __builtin_amdgcn_mfma_f32_16x16x32_bf16(vf[ct][1], P1, o[rt][ct], 0, 0, 0);
            }
        }

        if (more) {
            #pragma unroll
            for (int jt = 0; jt < 4; jt++) {
                kf[jt][0] = kn[jt][0];
                kf[jt][1] = kn[jt][1];
            }
        }
    }

    #pragma unroll
    for (int rt = 0; rt < 2; rt++) {
        l_[rt] += __shfl_xor(l_[rt], 16);
        l_[rt] += __shfl_xor(l_[rt], 32);
    }

    #pragma unroll
    for (int rt = 0; rt < 2; rt++) {
        #pragma unroll
        for (int ct = 0; ct < 4; ct++) Ol[w][ct][lane] = o[rt][ct];
        if (lc == 0) Ll[w][lr] = l_[rt];
        __syncthreads();

        {
            const int ct = w;
            float ltot = (Ll[0][lr] + Ll[1][lr]) + (Ll[2][lr] + Ll[3][lr]);
            float inv = 1.f / fmaxf(ltot, 1e-20f);
            float4v a0 = Ol[0][ct][lane], a1 = Ol[1][ct][lane];
            float4v a2 = Ol[2][ct][lane], a3 = Ol[3][ct][lane];
            int qrow = q0 + rt * 16 + lr;
            ushort4 u;
            u.x = f2bf(((a0[0] + a1[0]) + (a2[0] + a3[0])) * inv);
            u.y = f2bf(((a0[1] + a1[1]) + (a2[1] + a3[1])) * inv);
            u.z = f2bf(((a0[2] + a1[2]) + (a2[2] + a3[2])) * inv);
            u.w = f2bf(((a0[3] + a1[3]) + (a2[3] + a3[3])) * inv);
            *(ushort4*)&Yb[((size_t)b * TT + qrow) * CC + h * 64 + ct * 16 + lc * 4] = u;
        }
        if (rt == 0) __syncthreads();
    }
}

// ---------------------------------------------------------------------------
extern "C" void kernel_launch(void* const* d_in, const int* in_sizes, int n_in,
                              void* d_out, int out_size, void* d_ws, size_t ws_size,
                              hipStream_t stream) {
    (void)in_sizes; (void)n_in; (void)out_size; (void)ws_size;
    const float* x     = (const float*)d_in[0];
    const float* ve    = (const float*)d_in[1];
    const float* cosb  = (const float*)d_in[2];
    const float* sinb  = (const float*)d_in[3];
    const float* Wq    = (const float*)d_in[4];
    const float* Wk    = (const float*)d_in[5];
    const float* Wv    = (const float*)d_in[6];
    const float* Wproj = (const float*)d_in[7];
    const float* Wgate = (const float*)d_in[8];
    const int*   winp  = (const int*)d_in[9];
    float* out = (float*)d_out;

    char* ws = (char*)d_ws;
    ushort* Yb    = (ushort*)ws;                     // 8 MiB (attn out)
    float*  gateP = (float*)(ws + 8388608);          // 128 KiB (prep -> qkv epi)
    ushort* xb    = (ushort*)(ws + 33554432);        // 8 MiB bf16 x
    ushort* WqkvT = (ushort*)(ws + 41943040);        // 4 MiB: [2048][1024] = W^T
    ushort* WpT   = (ushort*)(ws + 46137344);        // 2 MiB: [1024][1024] = Wproj^T
    ushort* Qb    = (ushort*)(ws + 48234496);        // 8 MiB
    ushort* Kb    = (ushort*)(ws + 56623104);        // 4 MiB
    ushort* Vtb   = (ushort*)(ws + 60817408);        // 4 MiB (B,NKV,HD,T)

    dim3 blk(256);
    prep_kernel<<<dim3(4864), blk, 0, stream>>>(x, xb, Wq, Wk, Wv, Wproj, Wgate, WqkvT, WpT, gateP);
    // fused QKV projection + RoPE/RMSNorm/gate epilogue; V written directly as V^T
    gemm_qkv_kernel<<<dim3(32, 16), blk, 0, stream>>>(xb, WqkvT, cosb, sinb, gateP, ve, Qb, Kb, Vtb);
    // attention: static mapping + T1 XCD-panel swizzle (frozen)
    attn_kernel<<<dim3(2048), blk, 0, stream>>>(Qb, Kb, Vtb, Yb, winp);
    // output projection -> f32 d_out (r4 form)
    gemm_bt_kernel<64, 0><<<dim3(64, 8), blk, 0, stream>>>(Yb, WpT, out, 4096, 1024, 1024, 1024);
}

// Round 12
// 202.419 us; speedup vs baseline: 1.0357x; 1.0357x over previous
//
#include <hip/hip_runtime.h>
#include <hip/hip_bf16.h>

// Problem constants (B=2, T=2048, C=1024, NH=16, NKV=8, HD=64, Q_PER_KV=2)
#define BB 2
#define TT 2048
#define CC 1024
#define NH 16
#define NKV 8
#define HD 64

typedef __attribute__((ext_vector_type(8))) short short8;   // 8 bf16 (MFMA A/B frag)
typedef __attribute__((ext_vector_type(4))) float float4v;  // MFMA C/D frag
typedef __attribute__((ext_vector_type(4))) unsigned int uint4v;

__device__ __forceinline__ ushort f2bf(float f) {
    __hip_bfloat16 h = __float2bfloat16(f);
    union { __hip_bfloat16 h; ushort u; } v; v.h = h; return v.u;
}
__device__ __forceinline__ float bf2f(ushort u) {
    union { unsigned int i; float f; } v; v.i = ((unsigned int)u) << 16; return v.f;
}

// exp2 on the transcendental pipe; scale is folded by caller.
__device__ __forceinline__ float fexp2(float x) {
#if __has_builtin(__builtin_amdgcn_exp2f)
    return __builtin_amdgcn_exp2f(x);
#else
    return __expf(x * 0.69314718056f);
#endif
}

// async global->LDS, 16B per lane; lptr must be wave-uniform, HW adds lane*16
__device__ __forceinline__ void gload16(const ushort* g, ushort* l) {
    __builtin_amdgcn_global_load_lds(
        (const __attribute__((address_space(1))) unsigned int*)g,
        (__attribute__((address_space(3))) unsigned int*)l, 16, 0, 0);
}

// ---------------------------------------------------------------------------
// Fused prep: x f32->bf16 conv + per-row gate (blocks 0..4095) + weight
// transposes (f32 [K][N] -> bf16 [N][K], 64x64 LDS tiles).
// ---------------------------------------------------------------------------
__device__ __forceinline__ void transpose_tile(
    const float* __restrict__ src, ushort* __restrict__ dst,
    int Kd, int Nd, int kt, int nt, float* tile /*[64][65]*/)
{
    const int tid = threadIdx.x;
    {
        int r = tid >> 2, c = (tid & 3) * 16;
        #pragma unroll
        for (int i = 0; i < 4; i++) {
            float4 v = *(const float4*)&src[(size_t)(kt + r) * Nd + nt + c + i * 4];
            tile[r * 65 + c + i * 4 + 0] = v.x;
            tile[r * 65 + c + i * 4 + 1] = v.y;
            tile[r * 65 + c + i * 4 + 2] = v.z;
            tile[r * 65 + c + i * 4 + 3] = v.w;
        }
    }
    __syncthreads();
    {
        int n = tid >> 2, k = (tid & 3) * 16;
        #pragma unroll
        for (int i = 0; i < 2; i++) {
            ushort u[8];
            #pragma unroll
            for (int j = 0; j < 8; j++) u[j] = f2bf(tile[(k + i * 8 + j) * 65 + n]);
            *(uint4*)&dst[(size_t)(nt + n) * Kd + kt + k + i * 8] = *(uint4*)u;
        }
    }
}

__global__ __launch_bounds__(256) void prep_kernel(
    const float* __restrict__ x, ushort* __restrict__ xb,
    const float* __restrict__ Wq, const float* __restrict__ Wk,
    const float* __restrict__ Wv, const float* __restrict__ Wproj,
    const float* __restrict__ wgate,
    ushort* __restrict__ WqkvT, ushort* __restrict__ WpT,
    float* __restrict__ gateP)
{
    __shared__ float tile[64 * 65];
    const int bid = blockIdx.x;
    if (bid < 4096) {
        int i = (bid * 256 + threadIdx.x) * 4;
        float4 v = *(const float4*)&x[i];
        xb[i + 0] = f2bf(v.x);
        xb[i + 1] = f2bf(v.y);
        xb[i + 2] = f2bf(v.z);
        xb[i + 3] = f2bf(v.w);
        // gate for this row: gate[bid][g] = 2*sigmoid(sum_i x[bid][i]*Wgate[i][g])
        {
            int g = threadIdx.x >> 5, ii = threadIdx.x & 31;
            float p = x[(size_t)bid * CC + ii] * wgate[ii * 8 + g];
            #pragma unroll
            for (int off = 16; off; off >>= 1) p += __shfl_down(p, off, 32);
            if (ii == 0) gateP[bid * 8 + g] = 2.f / (1.f + __expf(-p));
        }
        return;
    }
    int t = bid - 4096;
    if (t < 256) {
        transpose_tile(Wq, WqkvT, 1024, 1024, (t >> 4) * 64, (t & 15) * 64, tile);
    } else if (t < 384) {
        t -= 256;
        transpose_tile(Wk, WqkvT + (size_t)1024 * 1024, 1024, 512, (t >> 3) * 64, (t & 7) * 64, tile);
    } else if (t < 512) {
        t -= 384;
        transpose_tile(Wv, WqkvT + (size_t)1536 * 1024, 1024, 512, (t >> 3) * 64, (t & 7) * 64, tile);
    } else {
        t -= 512;
        transpose_tile(Wproj, WpT, 1024, 1024, (t >> 4) * 64, (t & 15) * 64, tile);
    }
}

// ---------------------------------------------------------------------------
// bf16 GEMM — EXACT r4 single-buffer BK=32 form (best measured: 203.1us
// total; the same-buffer stage->read hazard makes the compiler emit the
// pre-barrier vmcnt drain). All structural variants (dbuf r5/r6, BK=64
// r8/r9, BM=128 r3, explicit vmcnt0 r10) measured neutral-or-worse. FROZEN.
// ---------------------------------------------------------------------------
template<int BM, int OBF16>
__global__ __launch_bounds__(256) void gemm_bt_kernel(
    const ushort* __restrict__ A, const ushort* __restrict__ Bt,
    void* __restrict__ Cp, int M, int N, int K, int ldc)
{
    constexpr int RT = BM / 32;
    __shared__ ushort As[BM][32];
    __shared__ ushort Bs[128][32];

    const int m0 = blockIdx.x * BM;
    const int n0 = blockIdx.y * 128;
    const int tid = threadIdx.x;
    const int lane = tid & 63;
    const int w = tid >> 6;
    const int lr = lane & 15, lc = lane >> 4;
    const int wm = (w >> 1) * (BM / 2), wn = (w & 1) * 64;

    float4v acc[RT][4] = {};

    for (int k0 = 0; k0 < K; k0 += 32) {
        #pragma unroll
        for (int s = 0; s < BM / 64; s++) {
            int rb = w * (BM / 4) + s * 16;
            gload16(&A[(size_t)(m0 + rb + (lane >> 2)) * K + k0 + (lane & 3) * 8], &As[rb][0]);
        }
        #pragma unroll
        for (int s = 0; s < 2; s++) {
            int rb = w * 32 + s * 16;
            gload16(&Bt[(size_t)(n0 + rb + (lane >> 2)) * K + k0 + (lane & 3) * 8], &Bs[rb][0]);
        }
        __syncthreads();

        short8 af[RT], bf[4];
        #pragma unroll
        for (int t = 0; t < RT; t++)
            af[t] = *(const short8*)&As[wm + t * 16 + lr][lc * 8];
        #pragma unroll
        for (int t = 0; t < 4; t++)
            bf[t] = *(const short8*)&Bs[wn + t * 16 + lr][lc * 8];
        #pragma unroll
        for (int rt = 0; rt < RT; rt++)
            #pragma unroll
            for (int ct = 0; ct < 4; ct++)
                acc[rt][ct] = __builtin_amdgcn_mfma_f32_16x16x32_bf16(af[rt], bf[ct], acc[rt][ct], 0, 0, 0);
        __syncthreads();
    }

    #pragma unroll
    for (int rt = 0; rt < RT; rt++)
        #pragma unroll
        for (int ct = 0; ct < 4; ct++)
            #pragma unroll
            for (int r = 0; r < 4; r++) {
                int row = m0 + wm + rt * 16 + lc * 4 + r;
                int col = n0 + wn + ct * 16 + lr;
                if (OBF16) ((ushort*)Cp)[(size_t)row * ldc + col] = f2bf(acc[rt][ct][r]);
                else       ((float*)Cp)[(size_t)row * ldc + col] = acc[rt][ct][r];
            }
}

// ---------------------------------------------------------------------------
// Fused QKV GEMM — exact r4 form: single-buffer BK=32 loop; epilogue applies
// RoPE+RMSNorm (Q/K) or gate+ve add (V) on UNROUNDED f32 accumulators, with
// V written in NATURAL layout (coalesced). r11's direct-V^T scatter write
// (16-line scatter per store) cost ~+6us in gemm_qkv — more than the ~5us
// v_transpose kernel it replaced. Coalesced write + separate LDS-tiled
// transpose is the measured-best V path.
// ---------------------------------------------------------------------------
__global__ __launch_bounds__(256) void gemm_qkv_kernel(
    const ushort* __restrict__ A, const ushort* __restrict__ Bt,
    const float* __restrict__ cosb, const float* __restrict__ sinb,
    const float* __restrict__ gateP, const float* __restrict__ ve,
    ushort* __restrict__ Qb, ushort* __restrict__ Kb, ushort* __restrict__ Vn)
{
    constexpr int K = 1024;
    __shared__ ushort As[128][32];
    __shared__ ushort Bs[128][32];

    const int m0 = blockIdx.x * 128;
    const int n0 = blockIdx.y * 128;
    const int tid = threadIdx.x;
    const int lane = tid & 63;
    const int w = tid >> 6;
    const int lr = lane & 15, lc = lane >> 4;
    const int wm = (w >> 1) * 64, wn = (w & 1) * 64;

    float4v acc[4][4] = {};

    for (int k0 = 0; k0 < K; k0 += 32) {
        #pragma unroll
        for (int s = 0; s < 2; s++) {
            int rb = w * 32 + s * 16;
            gload16(&A[(size_t)(m0 + rb + (lane >> 2)) * K + k0 + (lane & 3) * 8], &As[rb][0]);
            gload16(&Bt[(size_t)(n0 + rb + (lane >> 2)) * K + k0 + (lane & 3) * 8], &Bs[rb][0]);
        }
        __syncthreads();

        short8 af[4], bf[4];
        #pragma unroll
        for (int t = 0; t < 4; t++)
            af[t] = *(const short8*)&As[wm + t * 16 + lr][lc * 8];
        #pragma unroll
        for (int t = 0; t < 4; t++)
            bf[t] = *(const short8*)&Bs[wn + t * 16 + lr][lc * 8];
        #pragma unroll
        for (int rt = 0; rt < 4; rt++)
            #pragma unroll
            for (int ct = 0; ct < 4; ct++)
                acc[rt][ct] = __builtin_amdgcn_mfma_f32_16x16x32_bf16(af[rt], bf[ct], acc[rt][ct], 0, 0, 0);
        __syncthreads();
    }

    const int cg = n0 + wn;        // wave col base, multiple of 64
    const int hh2 = cg >> 6;       // 0..15 Q head, 16..23 K head, 24..31 V head

    if (hh2 < 24) {
        // ---- Q/K: RoPE + RMSNorm on f32 acc ----
        #pragma unroll
        for (int rt = 0; rt < 4; rt++) {
            #pragma unroll
            for (int r = 0; r < 4; r++) {
                int row = m0 + wm + rt * 16 + lc * 4 + r;
                int b = row >> 11, t = row & 2047;
                float v0 = acc[rt][0][r], v1 = acc[rt][1][r];
                float v2 = acc[rt][2][r], v3 = acc[rt][3][r];
                const float* cp = &cosb[t * 32];
                const float* sp = &sinb[t * 32];
                float c0 = cp[lr], s0 = sp[lr];
                float c1 = cp[16 + lr], s1 = sp[16 + lr];
                float r0 = v0 * c0 + v2 * s0;          // out[d],    d = lr
                float r1 = v1 * c1 + v3 * s1;          // out[d],    d = 16+lr
                float r2 = v2 * c0 - v0 * s0;          // out[32+lr]
                float r3 = v3 * c1 - v1 * s1;          // out[48+lr]
                float ss = (r0 * r0 + r1 * r1) + (r2 * r2 + r3 * r3);
                ss += __shfl_xor(ss, 1);
                ss += __shfl_xor(ss, 2);
                ss += __shfl_xor(ss, 4);
                ss += __shfl_xor(ss, 8);
                float sc = rsqrtf(ss * (1.f / 64.f) + 1.1920929e-07f);
                ushort* op = (hh2 < 16)
                    ? &Qb[(((size_t)b * NH + hh2) * TT + t) * HD]
                    : &Kb[(((size_t)b * NKV + (hh2 - 16)) * TT + t) * HD];
                op[lr]      = f2bf(r0 * sc);
                op[16 + lr] = f2bf(r1 * sc);
                op[32 + lr] = f2bf(r2 * sc);
                op[48 + lr] = f2bf(r3 * sc);
            }
        }
    } else {
        // ---- V: gate + ve add, natural layout (coalesced) ----
        const int kvh = hh2 - 24;
        #pragma unroll
        for (int rt = 0; rt < 4; rt++) {
            #pragma unroll
            for (int r = 0; r < 4; r++) {
                int row = m0 + wm + rt * 16 + lc * 4 + r;
                int b = row >> 11, t = row & 2047;
                float g = gateP[row * 8 + kvh];
                const float* vp = &ve[(size_t)row * 512 + kvh * 64];
                ushort* op = &Vn[(((size_t)b * NKV + kvh) * TT + t) * HD];
                op[lr]      = f2bf(acc[rt][0][r] + g * vp[lr]);
                op[16 + lr] = f2bf(acc[rt][1][r] + g * vp[16 + lr]);
                op[32 + lr] = f2bf(acc[rt][2][r] + g * vp[32 + lr]);
                op[48 + lr] = f2bf(acc[rt][3][r] + g * vp[48 + lr]);
            }
        }
    }
}

// ---------------------------------------------------------------------------
// V natural (B,NKV,T,HD) -> V^T (B,NKV,HD,T): LDS-tiled, coalesced both ways.
// Restored (r11 lesson: fusing this as a scatter write costs more than the
// kernel itself).
// ---------------------------------------------------------------------------
__global__ __launch_bounds__(256) void v_transpose_kernel(
    const ushort* __restrict__ Vn, ushort* __restrict__ Vt)
{
    __shared__ ushort tile[64][72];
    const int t0 = blockIdx.x * 64;
    const int bh = blockIdx.y;
    const ushort* src = &Vn[(size_t)bh * TT * HD + (size_t)t0 * HD];
    ushort* dst = &Vt[(size_t)bh * HD * TT + t0];
    const int tid = threadIdx.x;
    {
        int r = tid >> 2, c = (tid & 3) * 16;
        #pragma unroll
        for (int i = 0; i < 2; i++)
            *(uint4*)&tile[r][c + i * 8] = *(const uint4*)&src[(size_t)r * HD + c + i * 8];
    }
    __syncthreads();
    {
        int d = tid >> 2, c = (tid & 3) * 16;
        #pragma unroll
        for (int i = 0; i < 2; i++) {
            ushort u[8];
            #pragma unroll
            for (int j = 0; j < 8; j++) u[j] = tile[c + i * 8 + j][d];
            *(uint4*)&dst[(size_t)d * TT + c + i * 8] = *(uint4*)u;
        }
    }
}

// ---------------------------------------------------------------------------
// Split-KV flash attention (static r4 inner structure, T12 in-reg P
// transpose) + T1 XCD-panel swizzle (FETCH 12.35->8.25 MB, attn-dur
// neutral; this round is its first clean pipeline-level isolation vs
// r4's 203.1 — r10/r11 both carried an unrelated +6us suspect). FROZEN
// otherwise: occupancy (r7), balance (r7), locality (r10) all measured
// neutral-or-worse on dur; kernel is dependency-latency-bound.
// ---------------------------------------------------------------------------
__global__ __launch_bounds__(256) void attn_kernel(
    const ushort* __restrict__ Qb, const ushort* __restrict__ Kb,
    const ushort* __restrict__ Vt, ushort* __restrict__ Yb,
    const int* __restrict__ winp)
{
    const int bid = blockIdx.x;
    const int p = bid & 7;          // XCD panel
    const int rank = bid >> 3;      // 0..255 within panel (heavy-first)
    const int rtype = rank >> 7;    // 0 = global heads, 1 = local heads
    const int rr = rank & 127;
    const int qw = 63 - (rr >> 1);
    const int h = (rtype ? 8 : 0) + (p >> 1) * 2 + (rr & 1);
    const int b = p & 1;

    const int q0 = qw * 32;
    const int kvh = h >> 1;
    const bool local = (h >= 8);
    int window = *winp;
    if (window < 0 || window > TT) window = TT;
    const int tid = threadIdx.x;
    const int w = tid >> 6;
    const int lane = tid & 63;
    const int lr = lane & 15, lc = lane >> 4;

    __shared__ float4v Ol[4][4][64];
    __shared__ float Ll[4][16];

    const ushort* qbase = &Qb[(((size_t)b * NH + h) * TT + q0) * HD];
    short8 qf[2][2];
    #pragma unroll
    for (int rt = 0; rt < 2; rt++)
        #pragma unroll
        for (int xh = 0; xh < 2; xh++)
            qf[rt][xh] = *(const short8*)&qbase[(size_t)(rt * 16 + lr) * HD + xh * 32 + lc * 8];

    float4v o[2][4] = {};
    float l_[2] = {0.f, 0.f};

    const ushort* Kbase = &Kb[((size_t)b * NKV + kvh) * TT * HD];
    const ushort* Vbase = &Vt[((size_t)b * NKV + kvh) * HD * TT];

    const int qlast = q0 + 31;
    int jstart = 0;
    if (local) { int js = q0 - window; if (js > 0) jstart = js & ~63; }
    const int j0first = jstart + w * 64;

    // softmax scale (1/8) folded into exp2: exp(x/8) = 2^(x * 0.125*log2(e))
    const float ESC = 0.1803368801f;

    short8 kf[4][2];
    if (j0first <= qlast) {
        #pragma unroll
        for (int jt = 0; jt < 4; jt++) {
            const ushort* kp = &Kbase[(size_t)(j0first + jt * 16 + lr) * HD + lc * 8];
            kf[jt][0] = *(const short8*)kp;
            kf[jt][1] = *(const short8*)(kp + 32);
        }
    }

    for (int j0 = j0first; j0 <= qlast; j0 += 256) {
        short8 vf[4][2];
        #pragma unroll
        for (int ct = 0; ct < 4; ct++) {
            const ushort* vp = &Vbase[(size_t)(ct * 16 + lr) * TT + j0 + lc * 8];
            vf[ct][0] = *(const short8*)vp;
            vf[ct][1] = *(const short8*)(vp + 32);
        }
        short8 kn[4][2];
        const bool more = (j0 + 256 <= qlast);
        if (more) {
            #pragma unroll
            for (int jt = 0; jt < 4; jt++) {
                const ushort* kp = &Kbase[(size_t)(j0 + 256 + jt * 16 + lr) * HD + lc * 8];
                kn[jt][0] = *(const short8*)kp;
                kn[jt][1] = *(const short8*)(kp + 32);
            }
        }

        float4v st[2][4];
        #pragma unroll
        for (int jt = 0; jt < 4; jt++)
            #pragma unroll
            for (int rt = 0; rt < 2; rt++) {
                float4v z = {};
                z = __builtin_amdgcn_mfma_f32_16x16x32_bf16(kf[jt][0], qf[rt][0], z, 0, 0, 0);
                z = __builtin_amdgcn_mfma_f32_16x16x32_bf16(kf[jt][1], qf[rt][1], z, 0, 0, 0);
                st[rt][jt] = z;
            }

        const bool need_c = (j0 + 63 > q0);
        const bool need_w = local && (j0 < qlast - window);

        #pragma unroll
        for (int rt = 0; rt < 2; rt++) {
            const int qrow = q0 + rt * 16 + lr;
            float p4[4][4];
            if (need_c || need_w) {
                #pragma unroll
                for (int jt = 0; jt < 4; jt++)
                    #pragma unroll
                    for (int r = 0; r < 4; r++) {
                        int key = j0 + jt * 16 + lc * 4 + r;
                        bool ok = (key <= qrow) && (!local || key >= qrow - window);
                        p4[jt][r] = ok ? fexp2(st[rt][jt][r] * ESC) : 0.f;
                    }
            } else {
                #pragma unroll
                for (int jt = 0; jt < 4; jt++)
                    #pragma unroll
                    for (int r = 0; r < 4; r++)
                        p4[jt][r] = fexp2(st[rt][jt][r] * ESC);
            }
            float s0 = (p4[0][0] + p4[0][1]) + (p4[0][2] + p4[0][3]);
            float s1 = (p4[1][0] + p4[1][1]) + (p4[1][2] + p4[1][3]);
            float s2 = (p4[2][0] + p4[2][1]) + (p4[2][2] + p4[2][3]);
            float s3 = (p4[3][0] + p4[3][1]) + (p4[3][2] + p4[3][3]);
            l_[rt] += (s0 + s1) + (s2 + s3);

            // ---- T12: in-register P -> B-fragment transpose ----
            unsigned int a0, a1, b0, b1, c0, c1, d0, d1;
            asm("v_cvt_pk_bf16_f32 %0, %1, %2" : "=v"(a0) : "v"(p4[0][0]), "v"(p4[0][1]));
            asm("v_cvt_pk_bf16_f32 %0, %1, %2" : "=v"(a1) : "v"(p4[0][2]), "v"(p4[0][3]));
            asm("v_cvt_pk_bf16_f32 %0, %1, %2" : "=v"(b0) : "v"(p4[1][0]), "v"(p4[1][1]));
            asm("v_cvt_pk_bf16_f32 %0, %1, %2" : "=v"(b1) : "v"(p4[1][2]), "v"(p4[1][3]));
            asm("v_cvt_pk_bf16_f32 %0, %1, %2" : "=v"(c0) : "v"(p4[2][0]), "v"(p4[2][1]));
            asm("v_cvt_pk_bf16_f32 %0, %1, %2" : "=v"(c1) : "v"(p4[2][2]), "v"(p4[2][3]));
            asm("v_cvt_pk_bf16_f32 %0, %1, %2" : "=v"(d0) : "v"(p4[3][0]), "v"(p4[3][1]));
            asm("v_cvt_pk_bf16_f32 %0, %1, %2" : "=v"(d1) : "v"(p4[3][2]), "v"(p4[3][3]));

            asm("v_permlane32_swap_b32 %0, %1" : "+v"(a0), "+v"(b0));
            asm("v_permlane16_swap_b32 %0, %1" : "+v"(a0), "+v"(b0));
            asm("v_permlane32_swap_b32 %0, %1" : "+v"(a1), "+v"(b1));
            asm("v_permlane16_swap_b32 %0, %1" : "+v"(a1), "+v"(b1));
            asm("v_permlane32_swap_b32 %0, %1" : "+v"(c0), "+v"(d0));
            asm("v_permlane16_swap_b32 %0, %1" : "+v"(c0), "+v"(d0));
            asm("v_permlane32_swap_b32 %0, %1" : "+v"(c1), "+v"(d1));
            asm("v_permlane16_swap_b32 %0, %1" : "+v"(c1), "+v"(d1));

            uint4v u0 = {a0, a1, b0, b1};
            uint4v u1 = {c0, c1, d0, d1};
            short8 P0 = __builtin_bit_cast(short8, u0);
            short8 P1 = __builtin_bit_cast(short8, u1);

            #pragma unroll
            for (int ct = 0; ct < 4; ct++) {
                o[rt][ct] = __builtin_amdgcn_mfma_f32_16x16x32_bf16(vf[ct][0], P0, o[rt][ct], 0, 0, 0);
                o[rt][ct] = __builtin_amdgcn_mfma_f32_16x16x32_bf16(vf[ct][1], P1, o[rt][ct], 0, 0, 0);
            }
        }

        if (more) {
            #pragma unroll
            for (int jt = 0; jt < 4; jt++) {
                kf[jt][0] = kn[jt][0];
                kf[jt][1] = kn[jt][1];
            }
        }
    }

    #pragma unroll
    for (int rt = 0; rt < 2; rt++) {
        l_[rt] += __shfl_xor(l_[rt], 16);
        l_[rt] += __shfl_xor(l_[rt], 32);
    }

    #pragma unroll
    for (int rt = 0; rt < 2; rt++) {
        #pragma unroll
        for (int ct = 0; ct < 4; ct++) Ol[w][ct][lane] = o[rt][ct];
        if (lc == 0) Ll[w][lr] = l_[rt];
        __syncthreads();

        {
            const int ct = w;
            float ltot = (Ll[0][lr] + Ll[1][lr]) + (Ll[2][lr] + Ll[3][lr]);
            float inv = 1.f / fmaxf(ltot, 1e-20f);
            float4v a0 = Ol[0][ct][lane], a1 = Ol[1][ct][lane];
            float4v a2 = Ol[2][ct][lane], a3 = Ol[3][ct][lane];
            int qrow = q0 + rt * 16 + lr;
            ushort4 u;
            u.x = f2bf(((a0[0] + a1[0]) + (a2[0] + a3[0])) * inv);
            u.y = f2bf(((a0[1] + a1[1]) + (a2[1] + a3[1])) * inv);
            u.z = f2bf(((a0[2] + a1[2]) + (a2[2] + a3[2])) * inv);
            u.w = f2bf(((a0[3] + a1[3]) + (a2[3] + a3[3])) * inv);
            *(ushort4*)&Yb[((size_t)b * TT + qrow) * CC + h * 64 + ct * 16 + lc * 4] = u;
        }
        if (rt == 0) __syncthreads();
    }
}

// ---------------------------------------------------------------------------
extern "C" void kernel_launch(void* const* d_in, const int* in_sizes, int n_in,
                              void* d_out, int out_size, void* d_ws, size_t ws_size,
                              hipStream_t stream) {
    (void)in_sizes; (void)n_in; (void)out_size; (void)ws_size;
    const float* x     = (const float*)d_in[0];
    const float* ve    = (const float*)d_in[1];
    const float* cosb  = (const float*)d_in[2];
    const float* sinb  = (const float*)d_in[3];
    const float* Wq    = (const float*)d_in[4];
    const float* Wk    = (const float*)d_in[5];
    const float* Wv    = (const float*)d_in[6];
    const float* Wproj = (const float*)d_in[7];
    const float* Wgate = (const float*)d_in[8];
    const int*   winp  = (const int*)d_in[9];
    float* out = (float*)d_out;

    char* ws = (char*)d_ws;
    ushort* Yb    = (ushort*)ws;                     // 8 MiB (attn out)
    float*  gateP = (float*)(ws + 8388608);          // 128 KiB (prep -> qkv epi)
    ushort* Vnb   = (ushort*)(ws + 12582912);        // 4 MiB natural V (epi out)
    ushort* xb    = (ushort*)(ws + 33554432);        // 8 MiB bf16 x
    ushort* WqkvT = (ushort*)(ws + 41943040);        // 4 MiB: [2048][1024] = W^T
    ushort* WpT   = (ushort*)(ws + 46137344);        // 2 MiB: [1024][1024] = Wproj^T
    ushort* Qb    = (ushort*)(ws + 48234496);        // 8 MiB
    ushort* Kb    = (ushort*)(ws + 56623104);        // 4 MiB
    ushort* Vtb   = (ushort*)(ws + 60817408);        // 4 MiB (B,NKV,HD,T)

    dim3 blk(256);
    prep_kernel<<<dim3(4864), blk, 0, stream>>>(x, xb, Wq, Wk, Wv, Wproj, Wgate, WqkvT, WpT, gateP);
    // fused QKV projection + RoPE/RMSNorm/gate epilogue -> Qb/Kb/Vnb (r4 form)
    gemm_qkv_kernel<<<dim3(32, 16), blk, 0, stream>>>(xb, WqkvT, cosb, sinb, gateP, ve, Qb, Kb, Vnb);
    v_transpose_kernel<<<dim3(TT / 64, BB * NKV), blk, 0, stream>>>(Vnb, Vtb);
    // attention: static mapping + T1 XCD-panel swizzle
    attn_kernel<<<dim3(2048), blk, 0, stream>>>(Qb, Kb, Vtb, Yb, winp);
    // output projection -> f32 d_out (r4 form)
    gemm_bt_kernel<64, 0><<<dim3(64, 8), blk, 0, stream>>>(Yb, WpT, out, 4096, 1024, 1024, 1024);
}